// Round 5
// baseline (228.842 us; speedup 1.0000x reference)
//
#include <hip/hip_runtime.h>
#include <math.h>

#define BATCH 4
#define SEQ   1024
#define CH    1024
#define NH    16
#define HD    64
#define N3    3072

typedef unsigned short u16;
typedef unsigned int   u32;
typedef __attribute__((ext_vector_type(8))) __bf16 bf16x8;
typedef __attribute__((ext_vector_type(4))) float  f32x4;
typedef __attribute__((ext_vector_type(4))) u32    u32x4;

__device__ __forceinline__ u32 f2bf(float f) {
    u32 x = __float_as_uint(f);
    return (x + 0x7fffu + ((x >> 16) & 1u)) >> 16;   // RNE bf16
}

// async global -> LDS, 16B per lane; LDS dest = base + lane*16
__device__ __forceinline__ void gload_lds16(const u16* g, u16* l) {
    __builtin_amdgcn_global_load_lds(
        (const __attribute__((address_space(1))) void*)g,
        (__attribute__((address_space(3))) void*)l, 16, 0, 0);
}

// ---------------------------------------------------------------------------
// fp32 -> bf16 elementwise
// ---------------------------------------------------------------------------
__global__ __launch_bounds__(256) void conv_bf16_kernel(
    const float* __restrict__ in, u16* __restrict__ out, int n)
{
    int i = (blockIdx.x * 256 + threadIdx.x) * 8;
    if (i >= n) return;
    float4 a = *(const float4*)&in[i];
    float4 b = *(const float4*)&in[i + 4];
    int4 p;
    p.x = (int)(f2bf(a.x) | (f2bf(a.y) << 16));
    p.y = (int)(f2bf(a.z) | (f2bf(a.w) << 16));
    p.z = (int)(f2bf(b.x) | (f2bf(b.y) << 16));
    p.w = (int)(f2bf(b.z) | (f2bf(b.w) << 16));
    *(int4*)&out[i] = p;
}

// ---------------------------------------------------------------------------
// W [K][N] fp32 -> WT [N][K] bf16
// ---------------------------------------------------------------------------
__global__ __launch_bounds__(256) void transpose_conv_kernel(
    const float* __restrict__ W, u16* __restrict__ WT, int K, int N)
{
    __shared__ float tile[32][33];
    const int n0 = blockIdx.x * 32, k0 = blockIdx.y * 32;
    const int tx = threadIdx.x & 31, ty = threadIdx.x >> 5;
    #pragma unroll
    for (int p = 0; p < 4; p++)
        tile[ty + p * 8][tx] = W[(size_t)(k0 + ty + p * 8) * N + n0 + tx];
    __syncthreads();
    #pragma unroll
    for (int p = 0; p < 4; p++)
        WT[(size_t)(n0 + ty + p * 8) * K + k0 + tx] = (u16)f2bf(tile[tx][ty + p * 8]);
}

// ---------------------------------------------------------------------------
// v [B][H][T][64] bf16 -> vT [B][H][64][T] bf16   (64x64 tile per block)
// ---------------------------------------------------------------------------
__global__ __launch_bounds__(256) void transpose_v_kernel(
    const u16* __restrict__ v, u16* __restrict__ vt)
{
    __shared__ u16 tile[64][72];
    const int bh = blockIdx.x >> 4, tt = blockIdx.x & 15;
    const int t0 = tt * 64;
    const int r = threadIdx.x >> 2, c = (threadIdx.x & 3) * 16;
    const u16* src = v + ((size_t)bh * SEQ + t0) * HD;
    *(int4*)&tile[r][c]     = *(const int4*)&src[(size_t)r * HD + c];
    *(int4*)&tile[r][c + 8] = *(const int4*)&src[(size_t)r * HD + c + 8];
    __syncthreads();
    const int d = r, c2 = c;   // write row d, t-chunk c2..c2+15
    u32 buf[8];
    #pragma unroll
    for (int q = 0; q < 8; q++)
        buf[q] = (u32)tile[c2 + 2 * q][d] | ((u32)tile[c2 + 2 * q + 1][d] << 16);
    u16* dst = vt + ((size_t)bh * HD + d) * SEQ + t0 + c2;
    *(int4*)dst       = make_int4((int)buf[0], (int)buf[1], (int)buf[2], (int)buf[3]);
    *(int4*)(dst + 8) = make_int4((int)buf[4], (int)buf[5], (int)buf[6], (int)buf[7]);
}

// ---------------------------------------------------------------------------
// MFMA GEMM qkv: 128x128 tile, 4 waves, BK=32, global_load_lds staging.
// ---------------------------------------------------------------------------
__global__ __launch_bounds__(256) void gemm_qkv_mfma(
    const u16* __restrict__ A, const u16* __restrict__ BT,
    u16* __restrict__ qb, u16* __restrict__ kbuf, u16* __restrict__ vbuf)
{
    __shared__ __align__(16) u16 As[128 * 32];
    __shared__ __align__(16) u16 Bs[128 * 32];

    const int tid = threadIdx.x;
    const int lane = tid & 63;
    const int w = tid >> 6;
    const int wr = w >> 1, wc = w & 1;
    const int m0 = blockIdx.y * 128, n0 = blockIdx.x * 128;

    const int srow = lane >> 2;
    const int sk   = (lane & 3) * 8;
    const u16* gA0 = A  + (size_t)(m0 + w * 16 + srow) * CH + sk;
    const u16* gA1 = A  + (size_t)(m0 + (w + 4) * 16 + srow) * CH + sk;
    const u16* gB0 = BT + (size_t)(n0 + w * 16 + srow) * CH + sk;
    const u16* gB1 = BT + (size_t)(n0 + (w + 4) * 16 + srow) * CH + sk;
    u16* lA0 = As + w * 16 * 32;
    u16* lA1 = As + (w + 4) * 16 * 32;
    u16* lB0 = Bs + w * 16 * 32;
    u16* lB1 = Bs + (w + 4) * 16 * 32;

    const int ln = lane & 15, quad = lane >> 4;
    const int afo = (wr * 64 + ln) * 32 + quad * 8;
    const int bfo = (wc * 64 + ln) * 32 + quad * 8;

    f32x4 acc[4][4];
    #pragma unroll
    for (int i = 0; i < 4; i++)
        #pragma unroll
        for (int j = 0; j < 4; j++) acc[i][j] = (f32x4)(0.f);

    for (int k0 = 0; k0 < CH; k0 += 32) {
        __syncthreads();
        gload_lds16(gA0 + k0, lA0);
        gload_lds16(gA1 + k0, lA1);
        gload_lds16(gB0 + k0, lB0);
        gload_lds16(gB1 + k0, lB1);
        __syncthreads();
        bf16x8 af[4], bfr[4];
        #pragma unroll
        for (int mi = 0; mi < 4; mi++) af[mi]  = *(const bf16x8*)&As[afo + mi * 512];
        #pragma unroll
        for (int ni = 0; ni < 4; ni++) bfr[ni] = *(const bf16x8*)&Bs[bfo + ni * 512];
        #pragma unroll
        for (int mi = 0; mi < 4; mi++)
            #pragma unroll
            for (int ni = 0; ni < 4; ni++)
                acc[mi][ni] = __builtin_amdgcn_mfma_f32_16x16x32_bf16(
                    af[mi], bfr[ni], acc[mi][ni], 0, 0, 0);
    }

    #pragma unroll
    for (int ni = 0; ni < 4; ni++) {
        const int n = n0 + wc * 64 + ni * 16 + ln;
        const int which = n >> 10;
        const int h = (n >> 6) & 15;
        const int d = n & 63;
        u16* dst = (which == 0) ? qb : (which == 1) ? kbuf : vbuf;
        #pragma unroll
        for (int mi = 0; mi < 4; mi++) {
            #pragma unroll
            for (int r = 0; r < 4; r++) {
                const int m = m0 + wr * 64 + mi * 16 + quad * 4 + r;
                const int b = m >> 10, t = m & 1023;
                dst[(((size_t)(b * NH + h)) * SEQ + t) * HD + d] =
                    (u16)f2bf(acc[mi][ni][r]);
            }
        }
    }
}

// ---------------------------------------------------------------------------
// MFMA GEMM proj: 64x128 tile (grid 512 -> 2 blocks/CU), fp32 out.
// ---------------------------------------------------------------------------
__global__ __launch_bounds__(256) void gemm_proj_mfma(
    const u16* __restrict__ A, const u16* __restrict__ BT, float* __restrict__ out)
{
    __shared__ __align__(16) u16 As[64 * 32];
    __shared__ __align__(16) u16 Bs[128 * 32];

    const int tid = threadIdx.x;
    const int lane = tid & 63;
    const int w = tid >> 6;
    const int wr = w >> 1, wc = w & 1;
    const int m0 = blockIdx.y * 64, n0 = blockIdx.x * 128;

    const int srow = lane >> 2;
    const int sk   = (lane & 3) * 8;
    const u16* gA0 = A  + (size_t)(m0 + w * 16 + srow) * CH + sk;
    const u16* gB0 = BT + (size_t)(n0 + w * 16 + srow) * CH + sk;
    const u16* gB1 = BT + (size_t)(n0 + (w + 4) * 16 + srow) * CH + sk;
    u16* lA0 = As + w * 16 * 32;
    u16* lB0 = Bs + w * 16 * 32;
    u16* lB1 = Bs + (w + 4) * 16 * 32;

    const int ln = lane & 15, quad = lane >> 4;
    const int afo = (wr * 32 + ln) * 32 + quad * 8;
    const int bfo = (wc * 64 + ln) * 32 + quad * 8;

    f32x4 acc[2][4];
    #pragma unroll
    for (int i = 0; i < 2; i++)
        #pragma unroll
        for (int j = 0; j < 4; j++) acc[i][j] = (f32x4)(0.f);

    for (int k0 = 0; k0 < CH; k0 += 32) {
        __syncthreads();
        gload_lds16(gA0 + k0, lA0);
        gload_lds16(gB0 + k0, lB0);
        gload_lds16(gB1 + k0, lB1);
        __syncthreads();
        bf16x8 af[2], bfr[4];
        #pragma unroll
        for (int mi = 0; mi < 2; mi++) af[mi]  = *(const bf16x8*)&As[afo + mi * 512];
        #pragma unroll
        for (int ni = 0; ni < 4; ni++) bfr[ni] = *(const bf16x8*)&Bs[bfo + ni * 512];
        #pragma unroll
        for (int mi = 0; mi < 2; mi++)
            #pragma unroll
            for (int ni = 0; ni < 4; ni++)
                acc[mi][ni] = __builtin_amdgcn_mfma_f32_16x16x32_bf16(
                    af[mi], bfr[ni], acc[mi][ni], 0, 0, 0);
    }

    #pragma unroll
    for (int ni = 0; ni < 4; ni++) {
        const int n = n0 + wc * 64 + ni * 16 + ln;
        #pragma unroll
        for (int mi = 0; mi < 2; mi++) {
            #pragma unroll
            for (int r = 0; r < 4; r++) {
                const int m = m0 + wr * 32 + mi * 16 + quad * 4 + r;
                out[(size_t)m * CH + n] = acc[mi][ni][r];
            }
        }
    }
}

// ---------------------------------------------------------------------------
// MFMA flash attention, barrier-free j-loop.
// Block = (bh, 64 q-rows), 4 independent waves x 16 rows.
// K frags + V^T frags read directly from global (L1-cached).
// P round-trips through wave-private XOR-swizzled LDS.
// ---------------------------------------------------------------------------
__global__ __launch_bounds__(256) void attn_mfma_kernel(
    const u16* __restrict__ qg, const u16* __restrict__ kg,
    const u16* __restrict__ vt,
    const float* __restrict__ span_params, const float* __restrict__ stride_params,
    u16* __restrict__ yb)
{
    __shared__ float tab[1056];                    // rel+32 -> mask weight
    __shared__ __align__(16) u16 Ps[4][16 * 64];   // per-wave P, XOR-swizzled

    const int tid  = threadIdx.x;
    const int lane = tid & 63;
    const int w    = tid >> 6;
    const int ln   = lane & 15, quad = lane >> 4;

    const int blk = blockIdx.x;
    const int it  = blk & 15;
    const int bh  = blk >> 4;
    const int h   = bh & (NH - 1);
    const int b   = bh >> 4;
    const int it0 = it << 6;
    const int row_base = it0 + (w << 4);

    const float span  = 1024.f / (1.f + __expf(-span_params[h]));
    const float limit = 32.f + span;
    const float e0 = __expf(stride_params[2 * h + 0]);
    const float e1 = __expf(stride_params[2 * h + 1]);
    const float inv_e = 1.f / (e0 + e1);
    const float sw0 = e0 * inv_e, sw1 = e1 * inv_e;

    for (int i = tid; i < 1056; i += 256) {
        int rel = i - 32;
        float clipv = fminf(fmaxf((limit - (float)rel) * (1.f / 32.f), 0.f), 1.f);
        tab[i] = (rel < 0) ? 0.f : clipv * (sw0 + ((rel & 1) ? 0.f : sw1));
    }

    const size_t hb  = (size_t)bh * SEQ;
    const size_t hvt = (size_t)bh * HD;

    const u16* qp = qg + (hb + row_base + ln) * HD + quad * 8;
    bf16x8 aq0 = *(const bf16x8*)qp;
    bf16x8 aq1 = *(const bf16x8*)(qp + 32);

    u32x4 onesw; onesw.x = onesw.y = onesw.z = onesw.w = 0x3f803f80u;
    const bf16x8 onesf = __builtin_bit_cast(bf16x8, onesw);

    f32x4 acc_o[4];
    #pragma unroll
    for (int di = 0; di < 4; di++) acc_o[di] = (f32x4)(0.f);
    f32x4 acc_s = (f32x4)(0.f);

    int jmin = it0 - (int)limit - 1;
    if (jmin < 0) jmin = 0;
    const int jt0 = jmin & ~63;

    u16* Psw = Ps[w];
    const int lm7 = ln & 7;

    __syncthreads();   // tab ready (only barrier)

    for (int jt = jt0; jt <= it0; jt += 64) {
        // ---- issue all K / V^T fragment loads for this tile ----
        bf16x8 kf[4][2], vf[4][2];
        #pragma unroll
        for (int ni = 0; ni < 4; ni++) {
            const u16* kp = kg + (hb + jt + ni * 16 + ln) * HD + quad * 8;
            kf[ni][0] = *(const bf16x8*)kp;
            kf[ni][1] = *(const bf16x8*)(kp + 32);
        }
        #pragma unroll
        for (int di = 0; di < 4; di++) {
            const u16* vp = vt + (hvt + di * 16 + ln) * SEQ + jt + quad * 8;
            vf[di][0] = *(const bf16x8*)vp;
            vf[di][1] = *(const bf16x8*)(vp + 32);
        }

        // ---- skip flags (wave-uniform) ----
        bool sk[4];
        #pragma unroll
        for (int ni = 0; ni < 4; ni++) {
            const int col0 = jt + ni * 16;
            sk[ni] = (row_base + 15 < col0) ||
                     ((float)(row_base - (col0 + 15)) >= limit);
        }
        const bool nz0 = !sk[0] || !sk[1];
        const bool nz1 = !sk[2] || !sk[3];

        // ---- S = Q K^T, mask+exp, P -> swizzled LDS (wave-private) ----
        #pragma unroll
        for (int ni = 0; ni < 4; ni++) {
            const int col0 = jt + ni * 16;
            const int cbase = ni * 2 + (ln >> 3);   // chunk index 0..7
            if (sk[ni]) {
                if ((ni < 2) ? nz0 : nz1) {
                    #pragma unroll
                    for (int r = 0; r < 4; r++) {
                        const int il = quad * 4 + r;
                        Psw[il * 64 + (cbase ^ (il & 7)) * 8 + lm7] = 0;
                    }
                }
                continue;
            }
            f32x4 s = __builtin_amdgcn_mfma_f32_16x16x32_bf16(aq0, kf[ni][0], (f32x4)(0.f), 0, 0, 0);
            s = __builtin_amdgcn_mfma_f32_16x16x32_bf16(aq1, kf[ni][1], s, 0, 0, 0);
            #pragma unroll
            for (int r = 0; r < 4; r++) {
                const int il  = quad * 4 + r;
                const int rel = (row_base + il) - (col0 + ln);
                float wv = __expf(s[r] * 0.125f) * tab[rel + 32];
                Psw[il * 64 + (cbase ^ (il & 7)) * 8 + lm7] = (u16)f2bf(wv);
            }
        }

        // ---- O += P V, rowsum += P 1  (A-frags from swizzled LDS) ----
        if (nz0) {
            bf16x8 ap0 = *(const bf16x8*)&Psw[ln * 64 + (quad ^ lm7) * 8];
            acc_s = __builtin_amdgcn_mfma_f32_16x16x32_bf16(ap0, onesf, acc_s, 0, 0, 0);
            #pragma unroll
            for (int di = 0; di < 4; di++)
                acc_o[di] = __builtin_amdgcn_mfma_f32_16x16x32_bf16(ap0, vf[di][0], acc_o[di], 0, 0, 0);
        }
        if (nz1) {
            bf16x8 ap1 = *(const bf16x8*)&Psw[ln * 64 + ((quad + 4) ^ lm7) * 8];
            acc_s = __builtin_amdgcn_mfma_f32_16x16x32_bf16(ap1, onesf, acc_s, 0, 0, 0);
            #pragma unroll
            for (int di = 0; di < 4; di++)
                acc_o[di] = __builtin_amdgcn_mfma_f32_16x16x32_bf16(ap1, vf[di][1], acc_o[di], 0, 0, 0);
        }
    }

    #pragma unroll
    for (int r = 0; r < 4; r++) {
        const int t = row_base + quad * 4 + r;
        const float inv = 1.f / acc_s[r];
        const size_t rowoff = ((size_t)(b * SEQ + t)) * CH + h * HD;
        #pragma unroll
        for (int di = 0; di < 4; di++)
            yb[rowoff + di * 16 + ln] = (u16)f2bf(acc_o[di][r] * inv);
    }
}

__global__ void span_loss_kernel(const float* __restrict__ sp, float* __restrict__ out)
{
    if (threadIdx.x == 0 && blockIdx.x == 0) {
        float s = 0.f;
        for (int h = 0; h < NH; h++) {
            float sig = 1.f / (1.f + __expf(-sp[h]));
            s += sig * 1024.f;
        }
        out[0] = 2e-6f * s / (float)NH;
    }
}

extern "C" void kernel_launch(void* const* d_in, const int* in_sizes, int n_in,
                              void* d_out, int out_size, void* d_ws, size_t ws_size,
                              hipStream_t stream)
{
    const float* x            = (const float*)d_in[0];
    const float* Wqkv         = (const float*)d_in[1];
    const float* Wproj        = (const float*)d_in[2];
    const float* span_params  = (const float*)d_in[3];
    const float* stride_param = (const float*)d_in[4];
    float* out = (float*)d_out;

    const size_t SZ = (size_t)BATCH * NH * SEQ * HD;  // 4,194,304
    u16* base = (u16*)d_ws;
    u16* qb  = base;                    // bf16 [B][H][T][64]
    u16* kb  = qb + SZ;
    u16* vb  = kb + SZ;
    u16* vtb = vb + SZ;                 // bf16 [B][H][64][T]
    u16* yb  = vtb + SZ;                // bf16 [B][T][C]
    u16* xb  = yb + SZ;                 // bf16 x
    u16* wqT = xb + SZ;                 // bf16 [3072][1024]
    u16* wpT = wqT + (size_t)CH * N3;   // bf16 [1024][1024]

    conv_bf16_kernel<<<dim3((int)(SZ / (256 * 8))), 256, 0, stream>>>(x, xb, (int)SZ);
    transpose_conv_kernel<<<dim3(N3 / 32, CH / 32), 256, 0, stream>>>(Wqkv, wqT, CH, N3);
    transpose_conv_kernel<<<dim3(CH / 32, CH / 32), 256, 0, stream>>>(Wproj, wpT, CH, CH);

    gemm_qkv_mfma<<<dim3(N3 / 128, (BATCH * SEQ) / 128), 256, 0, stream>>>(
        xb, wqT, qb, kb, vb);

    transpose_v_kernel<<<dim3(BATCH * NH * (SEQ / 64)), 256, 0, stream>>>(vb, vtb);

    attn_mfma_kernel<<<dim3(BATCH * NH * (SEQ / 64)), 256, 0, stream>>>(
        qb, kb, vtb, span_params, stride_param, yb);

    gemm_proj_mfma<<<dim3(CH / 128, (BATCH * SEQ) / 64), 256, 0, stream>>>(
        yb, wpT, out);

    span_loss_kernel<<<1, 64, 0, stream>>>(span_params, out + SZ);
}

// Round 6
// 172.798 us; speedup vs baseline: 1.3243x; 1.3243x over previous
//
#include <hip/hip_runtime.h>
#include <math.h>

#define BATCH 4
#define SEQ   1024
#define CH    1024
#define NH    16
#define HD    64
#define N3    3072

typedef unsigned short u16;
typedef unsigned int   u32;
typedef __attribute__((ext_vector_type(8))) __bf16 bf16x8;
typedef __attribute__((ext_vector_type(4))) float  f32x4;
typedef __attribute__((ext_vector_type(4))) u32    u32x4;

__device__ __forceinline__ u32 f2bf(float f) {
    u32 x = __float_as_uint(f);
    return (x + 0x7fffu + ((x >> 16) & 1u)) >> 16;   // RNE bf16
}

// async global -> LDS, 16B per lane; LDS dest = wave-uniform base + lane*16
__device__ __forceinline__ void gload_lds16(const u16* g, u16* l) {
    __builtin_amdgcn_global_load_lds(
        (const __attribute__((address_space(1))) void*)g,
        (__attribute__((address_space(3))) void*)l, 16, 0, 0);
}

// ---------------------------------------------------------------------------
// fp32 -> bf16 elementwise
// ---------------------------------------------------------------------------
__global__ __launch_bounds__(256) void conv_bf16_kernel(
    const float* __restrict__ in, u16* __restrict__ out, int n)
{
    int i = (blockIdx.x * 256 + threadIdx.x) * 8;
    if (i >= n) return;
    float4 a = *(const float4*)&in[i];
    float4 b = *(const float4*)&in[i + 4];
    int4 p;
    p.x = (int)(f2bf(a.x) | (f2bf(a.y) << 16));
    p.y = (int)(f2bf(a.z) | (f2bf(a.w) << 16));
    p.z = (int)(f2bf(b.x) | (f2bf(b.y) << 16));
    p.w = (int)(f2bf(b.z) | (f2bf(b.w) << 16));
    *(int4*)&out[i] = p;
}

// ---------------------------------------------------------------------------
// W [K][N] fp32 -> WT [N][K] bf16
// ---------------------------------------------------------------------------
__global__ __launch_bounds__(256) void transpose_conv_kernel(
    const float* __restrict__ W, u16* __restrict__ WT, int K, int N)
{
    __shared__ float tile[32][33];
    const int n0 = blockIdx.x * 32, k0 = blockIdx.y * 32;
    const int tx = threadIdx.x & 31, ty = threadIdx.x >> 5;
    #pragma unroll
    for (int p = 0; p < 4; p++)
        tile[ty + p * 8][tx] = W[(size_t)(k0 + ty + p * 8) * N + n0 + tx];
    __syncthreads();
    #pragma unroll
    for (int p = 0; p < 4; p++)
        WT[(size_t)(n0 + ty + p * 8) * K + k0 + tx] = (u16)f2bf(tile[tx][ty + p * 8]);
}

// ---------------------------------------------------------------------------
// MFMA GEMM qkv: 128x128 tile, 4 waves, BK=32, global_load_lds staging.
// Epilogue: q,k -> [B][H][T][64]; v -> TRANSPOSED [B][H][64][T] (same store
// count as before, just different addresses — kills the transpose_v kernel).
// ---------------------------------------------------------------------------
__global__ __launch_bounds__(256) void gemm_qkv_mfma(
    const u16* __restrict__ A, const u16* __restrict__ BT,
    u16* __restrict__ qb, u16* __restrict__ kbuf, u16* __restrict__ vtb)
{
    __shared__ __align__(16) u16 As[128 * 32];
    __shared__ __align__(16) u16 Bs[128 * 32];

    const int tid = threadIdx.x;
    const int lane = tid & 63;
    const int w = tid >> 6;
    const int wr = w >> 1, wc = w & 1;
    const int m0 = blockIdx.y * 128, n0 = blockIdx.x * 128;

    const int srow = lane >> 2;
    const int sk   = (lane & 3) * 8;
    const u16* gA0 = A  + (size_t)(m0 + w * 16 + srow) * CH + sk;
    const u16* gA1 = A  + (size_t)(m0 + (w + 4) * 16 + srow) * CH + sk;
    const u16* gB0 = BT + (size_t)(n0 + w * 16 + srow) * CH + sk;
    const u16* gB1 = BT + (size_t)(n0 + (w + 4) * 16 + srow) * CH + sk;
    u16* lA0 = As + w * 16 * 32;
    u16* lA1 = As + (w + 4) * 16 * 32;
    u16* lB0 = Bs + w * 16 * 32;
    u16* lB1 = Bs + (w + 4) * 16 * 32;

    const int ln = lane & 15, quad = lane >> 4;
    const int afo = (wr * 64 + ln) * 32 + quad * 8;
    const int bfo = (wc * 64 + ln) * 32 + quad * 8;

    f32x4 acc[4][4];
    #pragma unroll
    for (int i = 0; i < 4; i++)
        #pragma unroll
        for (int j = 0; j < 4; j++) acc[i][j] = (f32x4)(0.f);

    for (int k0 = 0; k0 < CH; k0 += 32) {
        __syncthreads();
        gload_lds16(gA0 + k0, lA0);
        gload_lds16(gA1 + k0, lA1);
        gload_lds16(gB0 + k0, lB0);
        gload_lds16(gB1 + k0, lB1);
        __syncthreads();
        bf16x8 af[4], bfr[4];
        #pragma unroll
        for (int mi = 0; mi < 4; mi++) af[mi]  = *(const bf16x8*)&As[afo + mi * 512];
        #pragma unroll
        for (int ni = 0; ni < 4; ni++) bfr[ni] = *(const bf16x8*)&Bs[bfo + ni * 512];
        #pragma unroll
        for (int mi = 0; mi < 4; mi++)
            #pragma unroll
            for (int ni = 0; ni < 4; ni++)
                acc[mi][ni] = __builtin_amdgcn_mfma_f32_16x16x32_bf16(
                    af[mi], bfr[ni], acc[mi][ni], 0, 0, 0);
    }

    #pragma unroll
    for (int ni = 0; ni < 4; ni++) {
        const int n = n0 + wc * 64 + ni * 16 + ln;
        const int which = n >> 10;
        const int h = (n >> 6) & 15;
        const int d = n & 63;
        #pragma unroll
        for (int mi = 0; mi < 4; mi++) {
            #pragma unroll
            for (int r = 0; r < 4; r++) {
                const int m = m0 + wr * 64 + mi * 16 + quad * 4 + r;
                const int b = m >> 10, t = m & 1023;
                const u16 val = (u16)f2bf(acc[mi][ni][r]);
                if (which == 0)
                    qb[(((size_t)(b * NH + h)) * SEQ + t) * HD + d] = val;
                else if (which == 1)
                    kbuf[(((size_t)(b * NH + h)) * SEQ + t) * HD + d] = val;
                else
                    vtb[(((size_t)(b * NH + h)) * HD + d) * SEQ + t] = val;
            }
        }
    }
}

// ---------------------------------------------------------------------------
// MFMA GEMM proj: 64x128 tile, fp32 out.
// ---------------------------------------------------------------------------
__global__ __launch_bounds__(256) void gemm_proj_mfma(
    const u16* __restrict__ A, const u16* __restrict__ BT, float* __restrict__ out)
{
    __shared__ __align__(16) u16 As[64 * 32];
    __shared__ __align__(16) u16 Bs[128 * 32];

    const int tid = threadIdx.x;
    const int lane = tid & 63;
    const int w = tid >> 6;
    const int wr = w >> 1, wc = w & 1;
    const int m0 = blockIdx.y * 64, n0 = blockIdx.x * 128;

    const int srow = lane >> 2;
    const int sk   = (lane & 3) * 8;
    const u16* gA0 = A  + (size_t)(m0 + w * 16 + srow) * CH + sk;
    const u16* gB0 = BT + (size_t)(n0 + w * 16 + srow) * CH + sk;
    const u16* gB1 = BT + (size_t)(n0 + (w + 4) * 16 + srow) * CH + sk;
    u16* lA0 = As + w * 16 * 32;
    u16* lB0 = Bs + w * 16 * 32;
    u16* lB1 = Bs + (w + 4) * 16 * 32;

    const int ln = lane & 15, quad = lane >> 4;
    const int afo = (wr * 32 + ln) * 32 + quad * 8;
    const int bfo = (wc * 64 + ln) * 32 + quad * 8;

    f32x4 acc[2][4];
    #pragma unroll
    for (int i = 0; i < 2; i++)
        #pragma unroll
        for (int j = 0; j < 4; j++) acc[i][j] = (f32x4)(0.f);

    for (int k0 = 0; k0 < CH; k0 += 32) {
        __syncthreads();
        gload_lds16(gA0 + k0, lA0);
        gload_lds16(gB0 + k0, lB0);
        gload_lds16(gB1 + k0, lB1);
        __syncthreads();
        bf16x8 af[2], bfr[4];
        #pragma unroll
        for (int mi = 0; mi < 2; mi++) af[mi]  = *(const bf16x8*)&As[afo + mi * 512];
        #pragma unroll
        for (int ni = 0; ni < 4; ni++) bfr[ni] = *(const bf16x8*)&Bs[bfo + ni * 512];
        #pragma unroll
        for (int mi = 0; mi < 2; mi++)
            #pragma unroll
            for (int ni = 0; ni < 4; ni++)
                acc[mi][ni] = __builtin_amdgcn_mfma_f32_16x16x32_bf16(
                    af[mi], bfr[ni], acc[mi][ni], 0, 0, 0);
    }

    #pragma unroll
    for (int ni = 0; ni < 4; ni++) {
        const int n = n0 + wc * 64 + ni * 16 + ln;
        #pragma unroll
        for (int mi = 0; mi < 2; mi++) {
            #pragma unroll
            for (int r = 0; r < 4; r++) {
                const int m = m0 + wr * 32 + mi * 16 + quad * 4 + r;
                out[(size_t)m * CH + n] = acc[mi][ni][r];
            }
        }
    }
}

// ---------------------------------------------------------------------------
// MFMA flash attention v3.
// Block = (bh, 64 q-rows), heavy tiles dispatched first.
// K tile and V^T tile cooperatively staged per j-tile via global_load_lds
// (XOR swizzle folded into the GLOBAL address so the lane-ordered LDS dest
// yields conflict-free b128 fragment reads). Wave-private XOR-swizzled P.
// Mask computed arithmetically (note sw0+sw1 == 1).
// ---------------------------------------------------------------------------
__global__ __launch_bounds__(256) void attn_mfma_kernel(
    const u16* __restrict__ qg, const u16* __restrict__ kg,
    const u16* __restrict__ vt,
    const float* __restrict__ span_params, const float* __restrict__ stride_params,
    u16* __restrict__ yb)
{
    __shared__ __align__(16) u16 Ks[64 * 64];      // [j][d], chunk c at slot c^(j&7)
    __shared__ __align__(16) u16 Vs[64 * 64];      // [d][t], chunk c at slot c^(d&7)
    __shared__ __align__(16) u16 Ps[4][16 * 64];   // per-wave P, XOR-swizzled

    const int tid  = threadIdx.x;
    const int lane = tid & 63;
    const int w    = tid >> 6;
    const int ln   = lane & 15, quad = lane >> 4;
    const int lm7  = ln & 7;

    const int blk = blockIdx.x;
    const int bh  = blk & 63;                // same-it blocks contiguous,
    const int it  = 15 - (blk >> 6);         // heavy q-tiles dispatched first
    const int h   = bh & (NH - 1);
    const int b   = bh >> 4;
    const int it0 = it << 6;
    const int row_base = it0 + (w << 4);

    const float span  = 1024.f / (1.f + __expf(-span_params[h]));
    const float limit = 32.f + span;
    const float e0 = __expf(stride_params[2 * h + 0]);
    const float e1 = __expf(stride_params[2 * h + 1]);
    const float swO = e0 / (e0 + e1);        // odd-rel factor; even-rel factor = 1
    const float c1 = limit * (1.f / 32.f);   // clip = clamp(c1 - rel/32, 0, 1)

    const size_t hb  = (size_t)bh * SEQ;
    const size_t hvt = (size_t)bh * HD;

    // Q A-frags, register-resident
    const u16* qp = qg + (hb + row_base + ln) * HD + quad * 8;
    bf16x8 aq0 = *(const bf16x8*)qp;
    bf16x8 aq1 = *(const bf16x8*)(qp + 32);

    u32x4 onesw; onesw.x = onesw.y = onesw.z = onesw.w = 0x3f803f80u;
    const bf16x8 onesf = __builtin_bit_cast(bf16x8, onesw);

    f32x4 acc_o[4];
    #pragma unroll
    for (int di = 0; di < 4; di++) acc_o[di] = (f32x4)(0.f);
    f32x4 acc_s = (f32x4)(0.f);

    int jmin = it0 - (int)limit - 1;
    if (jmin < 0) jmin = 0;
    const int jt0 = jmin & ~63;

    // staging decomposition: each wave covers rows 8w..8w+7 (+32 for 2nd call)
    const int srow = lane >> 3;              // 0..7
    const int schk = lane & 7;
    const int cs   = schk ^ srow;            // swizzled source chunk
    const int ra   = w * 8 + srow;           // 0..31
    const u16* pk0 = kg + (hb + ra) * HD + cs * 8;
    const u16* pk1 = pk0 + 32 * HD;
    const u16* pv0 = vt + (hvt + ra) * SEQ + cs * 8;
    const u16* pv1 = pv0 + 32 * SEQ;
    u16* Ksw0 = Ks + w * 512;
    u16* Ksw1 = Ks + 2048 + w * 512;
    u16* Vsw0 = Vs + w * 512;
    u16* Vsw1 = Vs + 2048 + w * 512;

    u16* Psw = Ps[w];

    for (int jt = jt0; jt <= it0; jt += 64) {
        __syncthreads();                     // prior tile's LDS reads complete
        gload_lds16(pk0 + (size_t)jt * HD, Ksw0);
        gload_lds16(pk1 + (size_t)jt * HD, Ksw1);
        gload_lds16(pv0 + jt, Vsw0);
        gload_lds16(pv1 + jt, Vsw1);
        __syncthreads();                     // vmcnt drained -> tiles visible

        // ---- wave-uniform skip flags ----
        bool sk[4];
        #pragma unroll
        for (int ni = 0; ni < 4; ni++) {
            const int col0 = jt + ni * 16;
            sk[ni] = (row_base + 15 < col0) ||
                     ((float)(row_base - (col0 + 15)) >= limit);
        }
        const bool nz0 = !sk[0] || !sk[1];
        const bool nz1 = !sk[2] || !sk[3];

        // ---- S = Q K^T, mask+exp, P -> wave-private swizzled LDS ----
        #pragma unroll
        for (int ni = 0; ni < 4; ni++) {
            const int col0 = jt + ni * 16;
            const int cbase = ni * 2 + (ln >> 3);
            if (sk[ni]) {
                if ((ni < 2) ? nz0 : nz1) {
                    #pragma unroll
                    for (int r = 0; r < 4; r++) {
                        const int il = quad * 4 + r;
                        Psw[il * 64 + (cbase ^ (il & 7)) * 8 + lm7] = 0;
                    }
                }
                continue;
            }
            const int krow = ni * 16 + ln;
            bf16x8 bk0 = *(const bf16x8*)&Ks[krow * 64 + ((quad ^ lm7) * 8)];
            bf16x8 bk1 = *(const bf16x8*)&Ks[krow * 64 + (((quad + 4) ^ lm7) * 8)];
            f32x4 s = __builtin_amdgcn_mfma_f32_16x16x32_bf16(aq0, bk0, (f32x4)(0.f), 0, 0, 0);
            s = __builtin_amdgcn_mfma_f32_16x16x32_bf16(aq1, bk1, s, 0, 0, 0);
            #pragma unroll
            for (int r = 0; r < 4; r++) {
                const int il  = quad * 4 + r;
                const int rel = (row_base + il) - (col0 + ln);
                float clip = fminf(fmaxf(fmaf((float)rel, -(1.f / 32.f), c1), 0.f), 1.f);
                float fac  = (rel & 1) ? swO : 1.0f;
                float wt   = (rel < 0) ? 0.f : clip * fac;
                float wv   = __expf(s[r] * 0.125f) * wt;
                Psw[il * 64 + (cbase ^ (il & 7)) * 8 + lm7] = (u16)f2bf(wv);
            }
        }

        // ---- O += P V, rowsum += P 1 ----
        if (nz0) {
            bf16x8 ap0 = *(const bf16x8*)&Psw[ln * 64 + (quad ^ lm7) * 8];
            acc_s = __builtin_amdgcn_mfma_f32_16x16x32_bf16(ap0, onesf, acc_s, 0, 0, 0);
            #pragma unroll
            for (int di = 0; di < 4; di++) {
                const int vrow = di * 16 + ln;
                bf16x8 bv0 = *(const bf16x8*)&Vs[vrow * 64 + ((quad ^ lm7) * 8)];
                acc_o[di] = __builtin_amdgcn_mfma_f32_16x16x32_bf16(ap0, bv0, acc_o[di], 0, 0, 0);
            }
        }
        if (nz1) {
            bf16x8 ap1 = *(const bf16x8*)&Psw[ln * 64 + ((quad + 4) ^ lm7) * 8];
            acc_s = __builtin_amdgcn_mfma_f32_16x16x32_bf16(ap1, onesf, acc_s, 0, 0, 0);
            #pragma unroll
            for (int di = 0; di < 4; di++) {
                const int vrow = di * 16 + ln;
                bf16x8 bv1 = *(const bf16x8*)&Vs[vrow * 64 + (((quad + 4) ^ lm7) * 8)];
                acc_o[di] = __builtin_amdgcn_mfma_f32_16x16x32_bf16(ap1, bv1, acc_o[di], 0, 0, 0);
            }
        }
    }

    #pragma unroll
    for (int r = 0; r < 4; r++) {
        const int t = row_base + quad * 4 + r;
        const float inv = 1.f / acc_s[r];
        const size_t rowoff = ((size_t)(b * SEQ + t)) * CH + h * HD;
        #pragma unroll
        for (int di = 0; di < 4; di++)
            yb[rowoff + di * 16 + ln] = (u16)f2bf(acc_o[di][r] * inv);
    }
}

__global__ void span_loss_kernel(const float* __restrict__ sp, float* __restrict__ out)
{
    if (threadIdx.x == 0 && blockIdx.x == 0) {
        float s = 0.f;
        for (int h = 0; h < NH; h++) {
            float sig = 1.f / (1.f + __expf(-sp[h]));
            s += sig * 1024.f;
        }
        out[0] = 2e-6f * s / (float)NH;
    }
}

extern "C" void kernel_launch(void* const* d_in, const int* in_sizes, int n_in,
                              void* d_out, int out_size, void* d_ws, size_t ws_size,
                              hipStream_t stream)
{
    const float* x            = (const float*)d_in[0];
    const float* Wqkv         = (const float*)d_in[1];
    const float* Wproj        = (const float*)d_in[2];
    const float* span_params  = (const float*)d_in[3];
    const float* stride_param = (const float*)d_in[4];
    float* out = (float*)d_out;

    const size_t SZ = (size_t)BATCH * NH * SEQ * HD;  // 4,194,304
    u16* base = (u16*)d_ws;
    u16* qb  = base;                    // bf16 [B][H][T][64]
    u16* kb  = qb + SZ;
    u16* vtb = kb + SZ;                 // bf16 [B][H][64][T]
    u16* yb  = vtb + SZ;                // bf16 [B][T][C]
    u16* xb  = yb + SZ;                 // bf16 x
    u16* wqT = xb + SZ;                 // bf16 [3072][1024]
    u16* wpT = wqT + (size_t)CH * N3;   // bf16 [1024][1024]

    conv_bf16_kernel<<<dim3((int)(SZ / (256 * 8))), 256, 0, stream>>>(x, xb, (int)SZ);
    transpose_conv_kernel<<<dim3(N3 / 32, CH / 32), 256, 0, stream>>>(Wqkv, wqT, CH, N3);
    transpose_conv_kernel<<<dim3(CH / 32, CH / 32), 256, 0, stream>>>(Wproj, wpT, CH, CH);

    gemm_qkv_mfma<<<dim3(N3 / 128, (BATCH * SEQ) / 128), 256, 0, stream>>>(
        xb, wqT, qb, kb, vtb);

    attn_mfma_kernel<<<dim3(BATCH * NH * (SEQ / 64)), 256, 0, stream>>>(
        qb, kb, vtb, span_params, stride_param, yb);

    gemm_proj_mfma<<<dim3(CH / 128, (BATCH * SEQ) / 64), 256, 0, stream>>>(
        yb, wpT, out);

    span_loss_kernel<<<1, 64, 0, stream>>>(span_params, out + SZ);
}

// Round 7
// 164.656 us; speedup vs baseline: 1.3898x; 1.0494x over previous
//
#include <hip/hip_runtime.h>
#include <math.h>

#define BATCH 4
#define SEQ   1024
#define CH    1024
#define NH    16
#define HD    64
#define N3    3072

typedef unsigned short u16;
typedef unsigned int   u32;
typedef __attribute__((ext_vector_type(8))) __bf16 bf16x8;
typedef __attribute__((ext_vector_type(4))) float  f32x4;
typedef __attribute__((ext_vector_type(4))) u32    u32x4;

__device__ __forceinline__ u32 f2bf(float f) {
    u32 x = __float_as_uint(f);
    return (x + 0x7fffu + ((x >> 16) & 1u)) >> 16;   // RNE bf16
}

// async global -> LDS, 16B per lane; LDS dest = wave-uniform base + lane*16
__device__ __forceinline__ void gload_lds16(const u16* g, u16* l) {
    __builtin_amdgcn_global_load_lds(
        (const __attribute__((address_space(1))) void*)g,
        (__attribute__((address_space(3))) void*)l, 16, 0, 0);
}

// ---------------------------------------------------------------------------
// fp32 -> bf16 elementwise
// ---------------------------------------------------------------------------
__global__ __launch_bounds__(256) void conv_bf16_kernel(
    const float* __restrict__ in, u16* __restrict__ out, int n)
{
    int i = (blockIdx.x * 256 + threadIdx.x) * 8;
    if (i >= n) return;
    float4 a = *(const float4*)&in[i];
    float4 b = *(const float4*)&in[i + 4];
    int4 p;
    p.x = (int)(f2bf(a.x) | (f2bf(a.y) << 16));
    p.y = (int)(f2bf(a.z) | (f2bf(a.w) << 16));
    p.z = (int)(f2bf(b.x) | (f2bf(b.y) << 16));
    p.w = (int)(f2bf(b.z) | (f2bf(b.w) << 16));
    *(int4*)&out[i] = p;
}

// ---------------------------------------------------------------------------
// Both weights: W [1024][N] fp32 -> WT [N][1024] bf16, one launch
// ---------------------------------------------------------------------------
__global__ __launch_bounds__(256) void transpose_both_kernel(
    const float* __restrict__ Wqkv, const float* __restrict__ Wproj,
    u16* __restrict__ wqT, u16* __restrict__ wpT)
{
    __shared__ float tile[32][33];
    int bx = blockIdx.x;
    const float* W;
    u16* WT;
    int N;
    if (bx < N3 / 32) { W = Wqkv; WT = wqT; N = N3; }
    else              { bx -= N3 / 32; W = Wproj; WT = wpT; N = CH; }
    const int n0 = bx * 32, k0 = blockIdx.y * 32;
    const int tx = threadIdx.x & 31, ty = threadIdx.x >> 5;
    #pragma unroll
    for (int p = 0; p < 4; p++)
        tile[ty + p * 8][tx] = W[(size_t)(k0 + ty + p * 8) * N + n0 + tx];
    __syncthreads();
    #pragma unroll
    for (int p = 0; p < 4; p++)
        WT[(size_t)(n0 + ty + p * 8) * CH + k0 + tx] = (u16)f2bf(tile[tx][ty + p * 8]);
}

// ---------------------------------------------------------------------------
// MFMA GEMM qkv: 128x128 tile, 4 waves, BK=32, global_load_lds staging.
// Epilogue: q,k -> [B][H][T][64] (scalar, semi-coalesced); v -> TRANSPOSED
// [B][H][64][T] with packed 8B stores (lane holds 4 consecutive t in C-layout).
// ---------------------------------------------------------------------------
__global__ __launch_bounds__(256) void gemm_qkv_mfma(
    const u16* __restrict__ A, const u16* __restrict__ BT,
    u16* __restrict__ qb, u16* __restrict__ kbuf, u16* __restrict__ vtb)
{
    __shared__ __align__(16) u16 As[128 * 32];
    __shared__ __align__(16) u16 Bs[128 * 32];

    const int tid = threadIdx.x;
    const int lane = tid & 63;
    const int w = tid >> 6;
    const int wr = w >> 1, wc = w & 1;
    const int m0 = blockIdx.y * 128, n0 = blockIdx.x * 128;

    const int srow = lane >> 2;
    const int sk   = (lane & 3) * 8;
    const u16* gA0 = A  + (size_t)(m0 + w * 16 + srow) * CH + sk;
    const u16* gA1 = A  + (size_t)(m0 + (w + 4) * 16 + srow) * CH + sk;
    const u16* gB0 = BT + (size_t)(n0 + w * 16 + srow) * CH + sk;
    const u16* gB1 = BT + (size_t)(n0 + (w + 4) * 16 + srow) * CH + sk;
    u16* lA0 = As + w * 16 * 32;
    u16* lA1 = As + (w + 4) * 16 * 32;
    u16* lB0 = Bs + w * 16 * 32;
    u16* lB1 = Bs + (w + 4) * 16 * 32;

    const int ln = lane & 15, quad = lane >> 4;
    const int afo = (wr * 64 + ln) * 32 + quad * 8;
    const int bfo = (wc * 64 + ln) * 32 + quad * 8;

    f32x4 acc[4][4];
    #pragma unroll
    for (int i = 0; i < 4; i++)
        #pragma unroll
        for (int j = 0; j < 4; j++) acc[i][j] = (f32x4)(0.f);

    for (int k0 = 0; k0 < CH; k0 += 32) {
        __syncthreads();
        gload_lds16(gA0 + k0, lA0);
        gload_lds16(gA1 + k0, lA1);
        gload_lds16(gB0 + k0, lB0);
        gload_lds16(gB1 + k0, lB1);
        __syncthreads();
        bf16x8 af[4], bfr[4];
        #pragma unroll
        for (int mi = 0; mi < 4; mi++) af[mi]  = *(const bf16x8*)&As[afo + mi * 512];
        #pragma unroll
        for (int ni = 0; ni < 4; ni++) bfr[ni] = *(const bf16x8*)&Bs[bfo + ni * 512];
        #pragma unroll
        for (int mi = 0; mi < 4; mi++)
            #pragma unroll
            for (int ni = 0; ni < 4; ni++)
                acc[mi][ni] = __builtin_amdgcn_mfma_f32_16x16x32_bf16(
                    af[mi], bfr[ni], acc[mi][ni], 0, 0, 0);
    }

    const int which = (n0 >> 10);            // block-uniform (128 | 1024 tiles)
    if (which == 2) {
        // v: packed 4x bf16 (= 4 consecutive t) per 8B store into [B][H][64][T]
        #pragma unroll
        for (int ni = 0; ni < 4; ni++) {
            const int n = n0 + wc * 64 + ni * 16 + ln;
            const int h = (n >> 6) & 15;
            const int d = n & 63;
            #pragma unroll
            for (int mi = 0; mi < 4; mi++) {
                const int m = m0 + wr * 64 + mi * 16 + quad * 4;
                const int b = m >> 10, t = m & 1023;
                int2 pv;
                pv.x = (int)(f2bf(acc[mi][ni][0]) | (f2bf(acc[mi][ni][1]) << 16));
                pv.y = (int)(f2bf(acc[mi][ni][2]) | (f2bf(acc[mi][ni][3]) << 16));
                *(int2*)&vtb[(((size_t)(b * NH + h)) * HD + d) * SEQ + t] = pv;
            }
        }
    } else {
        u16* dst = (which == 0) ? qb : kbuf;
        #pragma unroll
        for (int ni = 0; ni < 4; ni++) {
            const int n = n0 + wc * 64 + ni * 16 + ln;
            const int h = (n >> 6) & 15;
            const int d = n & 63;
            #pragma unroll
            for (int mi = 0; mi < 4; mi++) {
                #pragma unroll
                for (int r = 0; r < 4; r++) {
                    const int m = m0 + wr * 64 + mi * 16 + quad * 4 + r;
                    const int b = m >> 10, t = m & 1023;
                    dst[(((size_t)(b * NH + h)) * SEQ + t) * HD + d] =
                        (u16)f2bf(acc[mi][ni][r]);
                }
            }
        }
    }
}

// ---------------------------------------------------------------------------
// MFMA GEMM proj: 64x128 tile, fp32 out. span_loss folded into block (0,0).
// ---------------------------------------------------------------------------
__global__ __launch_bounds__(256) void gemm_proj_mfma(
    const u16* __restrict__ A, const u16* __restrict__ BT, float* __restrict__ out,
    const float* __restrict__ sp, float* __restrict__ loss_out)
{
    __shared__ __align__(16) u16 As[64 * 32];
    __shared__ __align__(16) u16 Bs[128 * 32];

    const int tid = threadIdx.x;
    const int lane = tid & 63;
    const int w = tid >> 6;
    const int wr = w >> 1, wc = w & 1;
    const int m0 = blockIdx.y * 64, n0 = blockIdx.x * 128;

    if (blockIdx.x == 0 && blockIdx.y == 0 && tid == 0) {
        float s = 0.f;
        #pragma unroll
        for (int h = 0; h < NH; h++) {
            float sig = 1.f / (1.f + __expf(-sp[h]));
            s += sig * 1024.f;
        }
        loss_out[0] = 2e-6f * s / (float)NH;
    }

    const int srow = lane >> 2;
    const int sk   = (lane & 3) * 8;
    const u16* gA0 = A  + (size_t)(m0 + w * 16 + srow) * CH + sk;
    const u16* gB0 = BT + (size_t)(n0 + w * 16 + srow) * CH + sk;
    const u16* gB1 = BT + (size_t)(n0 + (w + 4) * 16 + srow) * CH + sk;
    u16* lA0 = As + w * 16 * 32;
    u16* lB0 = Bs + w * 16 * 32;
    u16* lB1 = Bs + (w + 4) * 16 * 32;

    const int ln = lane & 15, quad = lane >> 4;
    const int afo = (wr * 32 + ln) * 32 + quad * 8;
    const int bfo = (wc * 64 + ln) * 32 + quad * 8;

    f32x4 acc[2][4];
    #pragma unroll
    for (int i = 0; i < 2; i++)
        #pragma unroll
        for (int j = 0; j < 4; j++) acc[i][j] = (f32x4)(0.f);

    for (int k0 = 0; k0 < CH; k0 += 32) {
        __syncthreads();
        gload_lds16(gA0 + k0, lA0);
        gload_lds16(gB0 + k0, lB0);
        gload_lds16(gB1 + k0, lB1);
        __syncthreads();
        bf16x8 af[2], bfr[4];
        #pragma unroll
        for (int mi = 0; mi < 2; mi++) af[mi]  = *(const bf16x8*)&As[afo + mi * 512];
        #pragma unroll
        for (int ni = 0; ni < 4; ni++) bfr[ni] = *(const bf16x8*)&Bs[bfo + ni * 512];
        #pragma unroll
        for (int mi = 0; mi < 2; mi++)
            #pragma unroll
            for (int ni = 0; ni < 4; ni++)
                acc[mi][ni] = __builtin_amdgcn_mfma_f32_16x16x32_bf16(
                    af[mi], bfr[ni], acc[mi][ni], 0, 0, 0);
    }

    #pragma unroll
    for (int ni = 0; ni < 4; ni++) {
        const int n = n0 + wc * 64 + ni * 16 + ln;
        #pragma unroll
        for (int mi = 0; mi < 2; mi++) {
            #pragma unroll
            for (int r = 0; r < 4; r++) {
                const int m = m0 + wr * 32 + mi * 16 + quad * 4 + r;
                out[(size_t)m * CH + n] = acc[mi][ni][r];
            }
        }
    }
}

// ---------------------------------------------------------------------------
// MFMA flash attention v3 (unchanged from R6 — known-good).
// ---------------------------------------------------------------------------
__global__ __launch_bounds__(256) void attn_mfma_kernel(
    const u16* __restrict__ qg, const u16* __restrict__ kg,
    const u16* __restrict__ vt,
    const float* __restrict__ span_params, const float* __restrict__ stride_params,
    u16* __restrict__ yb)
{
    __shared__ __align__(16) u16 Ks[64 * 64];      // [j][d], chunk c at slot c^(j&7)
    __shared__ __align__(16) u16 Vs[64 * 64];      // [d][t], chunk c at slot c^(d&7)
    __shared__ __align__(16) u16 Ps[4][16 * 64];   // per-wave P, XOR-swizzled

    const int tid  = threadIdx.x;
    const int lane = tid & 63;
    const int w    = tid >> 6;
    const int ln   = lane & 15, quad = lane >> 4;
    const int lm7  = ln & 7;

    const int blk = blockIdx.x;
    const int bh  = blk & 63;                // same-it blocks contiguous,
    const int it  = 15 - (blk >> 6);         // heavy q-tiles dispatched first
    const int h   = bh & (NH - 1);
    const int b   = bh >> 4;
    const int it0 = it << 6;
    const int row_base = it0 + (w << 4);

    const float span  = 1024.f / (1.f + __expf(-span_params[h]));
    const float limit = 32.f + span;
    const float e0 = __expf(stride_params[2 * h + 0]);
    const float e1 = __expf(stride_params[2 * h + 1]);
    const float swO = e0 / (e0 + e1);        // odd-rel factor; even-rel factor = 1
    const float c1 = limit * (1.f / 32.f);   // clip = clamp(c1 - rel/32, 0, 1)

    const size_t hb  = (size_t)bh * SEQ;
    const size_t hvt = (size_t)bh * HD;

    const u16* qp = qg + (hb + row_base + ln) * HD + quad * 8;
    bf16x8 aq0 = *(const bf16x8*)qp;
    bf16x8 aq1 = *(const bf16x8*)(qp + 32);

    u32x4 onesw; onesw.x = onesw.y = onesw.z = onesw.w = 0x3f803f80u;
    const bf16x8 onesf = __builtin_bit_cast(bf16x8, onesw);

    f32x4 acc_o[4];
    #pragma unroll
    for (int di = 0; di < 4; di++) acc_o[di] = (f32x4)(0.f);
    f32x4 acc_s = (f32x4)(0.f);

    int jmin = it0 - (int)limit - 1;
    if (jmin < 0) jmin = 0;
    const int jt0 = jmin & ~63;

    const int srow = lane >> 3;              // 0..7
    const int schk = lane & 7;
    const int cs   = schk ^ srow;            // swizzled source chunk
    const int ra   = w * 8 + srow;           // 0..31
    const u16* pk0 = kg + (hb + ra) * HD + cs * 8;
    const u16* pk1 = pk0 + 32 * HD;
    const u16* pv0 = vt + (hvt + ra) * SEQ + cs * 8;
    const u16* pv1 = pv0 + 32 * SEQ;
    u16* Ksw0 = Ks + w * 512;
    u16* Ksw1 = Ks + 2048 + w * 512;
    u16* Vsw0 = Vs + w * 512;
    u16* Vsw1 = Vs + 2048 + w * 512;

    u16* Psw = Ps[w];

    for (int jt = jt0; jt <= it0; jt += 64) {
        __syncthreads();
        gload_lds16(pk0 + (size_t)jt * HD, Ksw0);
        gload_lds16(pk1 + (size_t)jt * HD, Ksw1);
        gload_lds16(pv0 + jt, Vsw0);
        gload_lds16(pv1 + jt, Vsw1);
        __syncthreads();

        bool sk[4];
        #pragma unroll
        for (int ni = 0; ni < 4; ni++) {
            const int col0 = jt + ni * 16;
            sk[ni] = (row_base + 15 < col0) ||
                     ((float)(row_base - (col0 + 15)) >= limit);
        }
        const bool nz0 = !sk[0] || !sk[1];
        const bool nz1 = !sk[2] || !sk[3];

        #pragma unroll
        for (int ni = 0; ni < 4; ni++) {
            const int col0 = jt + ni * 16;
            const int cbase = ni * 2 + (ln >> 3);
            if (sk[ni]) {
                if ((ni < 2) ? nz0 : nz1) {
                    #pragma unroll
                    for (int r = 0; r < 4; r++) {
                        const int il = quad * 4 + r;
                        Psw[il * 64 + (cbase ^ (il & 7)) * 8 + lm7] = 0;
                    }
                }
                continue;
            }
            const int krow = ni * 16 + ln;
            bf16x8 bk0 = *(const bf16x8*)&Ks[krow * 64 + ((quad ^ lm7) * 8)];
            bf16x8 bk1 = *(const bf16x8*)&Ks[krow * 64 + (((quad + 4) ^ lm7) * 8)];
            f32x4 s = __builtin_amdgcn_mfma_f32_16x16x32_bf16(aq0, bk0, (f32x4)(0.f), 0, 0, 0);
            s = __builtin_amdgcn_mfma_f32_16x16x32_bf16(aq1, bk1, s, 0, 0, 0);
            #pragma unroll
            for (int r = 0; r < 4; r++) {
                const int il  = quad * 4 + r;
                const int rel = (row_base + il) - (col0 + ln);
                float clip = fminf(fmaxf(fmaf((float)rel, -(1.f / 32.f), c1), 0.f), 1.f);
                float fac  = (rel & 1) ? swO : 1.0f;
                float wt   = (rel < 0) ? 0.f : clip * fac;
                float wv   = __expf(s[r] * 0.125f) * wt;
                Psw[il * 64 + (cbase ^ (il & 7)) * 8 + lm7] = (u16)f2bf(wv);
            }
        }

        if (nz0) {
            bf16x8 ap0 = *(const bf16x8*)&Psw[ln * 64 + (quad ^ lm7) * 8];
            acc_s = __builtin_amdgcn_mfma_f32_16x16x32_bf16(ap0, onesf, acc_s, 0, 0, 0);
            #pragma unroll
            for (int di = 0; di < 4; di++) {
                const int vrow = di * 16 + ln;
                bf16x8 bv0 = *(const bf16x8*)&Vs[vrow * 64 + ((quad ^ lm7) * 8)];
                acc_o[di] = __builtin_amdgcn_mfma_f32_16x16x32_bf16(ap0, bv0, acc_o[di], 0, 0, 0);
            }
        }
        if (nz1) {
            bf16x8 ap1 = *(const bf16x8*)&Psw[ln * 64 + ((quad + 4) ^ lm7) * 8];
            acc_s = __builtin_amdgcn_mfma_f32_16x16x32_bf16(ap1, onesf, acc_s, 0, 0, 0);
            #pragma unroll
            for (int di = 0; di < 4; di++) {
                const int vrow = di * 16 + ln;
                bf16x8 bv1 = *(const bf16x8*)&Vs[vrow * 64 + (((quad + 4) ^ lm7) * 8)];
                acc_o[di] = __builtin_amdgcn_mfma_f32_16x16x32_bf16(ap1, bv1, acc_o[di], 0, 0, 0);
            }
        }
    }

    #pragma unroll
    for (int r = 0; r < 4; r++) {
        const int t = row_base + quad * 4 + r;
        const float inv = 1.f / acc_s[r];
        const size_t rowoff = ((size_t)(b * SEQ + t)) * CH + h * HD;
        #pragma unroll
        for (int di = 0; di < 4; di++)
            yb[rowoff + di * 16 + ln] = (u16)f2bf(acc_o[di][r] * inv);
    }
}

extern "C" void kernel_launch(void* const* d_in, const int* in_sizes, int n_in,
                              void* d_out, int out_size, void* d_ws, size_t ws_size,
                              hipStream_t stream)
{
    const float* x            = (const float*)d_in[0];
    const float* Wqkv         = (const float*)d_in[1];
    const float* Wproj        = (const float*)d_in[2];
    const float* span_params  = (const float*)d_in[3];
    const float* stride_param = (const float*)d_in[4];
    float* out = (float*)d_out;

    const size_t SZ = (size_t)BATCH * NH * SEQ * HD;  // 4,194,304
    u16* base = (u16*)d_ws;
    u16* qb  = base;                    // bf16 [B][H][T][64]
    u16* kb  = qb + SZ;
    u16* vtb = kb + SZ;                 // bf16 [B][H][64][T]
    u16* yb  = vtb + SZ;                // bf16 [B][T][C]
    u16* xb  = yb + SZ;                 // bf16 x
    u16* wqT = xb + SZ;                 // bf16 [3072][1024]
    u16* wpT = wqT + (size_t)CH * N3;   // bf16 [1024][1024]

    conv_bf16_kernel<<<dim3((int)(SZ / (256 * 8))), 256, 0, stream>>>(x, xb, (int)SZ);
    transpose_both_kernel<<<dim3((N3 + CH) / 32, CH / 32), 256, 0, stream>>>(
        Wqkv, Wproj, wqT, wpT);

    gemm_qkv_mfma<<<dim3(N3 / 128, (BATCH * SEQ) / 128), 256, 0, stream>>>(
        xb, wqT, qb, kb, vtb);

    attn_mfma_kernel<<<dim3(BATCH * NH * (SEQ / 64)), 256, 0, stream>>>(
        qb, kb, vtb, span_params, stride_param, yb);

    gemm_proj_mfma<<<dim3(CH / 128, (BATCH * SEQ) / 64), 256, 0, stream>>>(
        yb, wpT, out, span_params, out + SZ);
}